// Round 3
// baseline (386561.035 us; speedup 1.0000x reference)
//
#include <hip/hip_runtime.h>
#include <hip/hip_bf16.h>

#define HID 2048
#define TSTEPS 1024
#define NBLK 256
#define NTHR 256

typedef unsigned long long ull;
typedef unsigned int u32;

__device__ __forceinline__ float reduce32(float v) {
    v += __shfl_xor(v, 16, 64);
    v += __shfl_xor(v, 8, 64);
    v += __shfl_xor(v, 4, 64);
    v += __shfl_xor(v, 2, 64);
    v += __shfl_xor(v, 1, 64);
    return v;
}

__global__ void __launch_bounds__(NTHR, 1)
ode_rnn_main(const float* __restrict__ x, const float* __restrict__ t,
             const float* __restrict__ W_in, const float* __restrict__ b_in,
             const float* __restrict__ W_hid, const float* __restrict__ b_hid,
             const float* __restrict__ W_ode, const float* __restrict__ b_ode,
             const float* __restrict__ W_dec, const float* __restrict__ b_dec,
             const int* __restrict__ nstep_p,
             ull* __restrict__ kb,                 // kb[2][HID] tagged values
             float* __restrict__ out)              // fp32 output (512)
{
    __shared__ float h_lds[HID];
    __shared__ float k_lds[HID];
    __shared__ float hacc[HID];

    const int tid  = threadIdx.x;
    const int bid  = blockIdx.x;
    const int g    = tid & 31;                     // lane within 32-group
    const int rloc = ((tid >> 6) << 1) | ((tid >> 5) & 1); // 0..7
    const int row  = bid * 8 + rloc;
    const int nstep = *nstep_p;

    // ---- W_ode row (64 regs) and W_in row (16 regs) ----
    float wode[64];
    {
        const float* wr = W_ode + (size_t)row * HID;
#pragma unroll
        for (int jj = 0; jj < 16; ++jj) {
            float4 v = *(const float4*)(wr + (g * 4 + jj * 128));
            wode[4*jj+0] = v.x; wode[4*jj+1] = v.y;
            wode[4*jj+2] = v.z; wode[4*jj+3] = v.w;
        }
    }
    float win[16];
    {
        const float* wr = W_in + (size_t)row * 512;
#pragma unroll
        for (int jj = 0; jj < 4; ++jj) {
            float4 v = *(const float4*)(wr + (g * 4 + jj * 128));
            win[4*jj+0] = v.x; win[4*jj+1] = v.y;
            win[4*jj+2] = v.z; win[4*jj+3] = v.w;
        }
    }
    const float breg = b_ode[row];
    const float bsum = b_in[row] + b_hid[row];
    const float* whid_row = W_hid + (size_t)row * HID;

    u32 rnd = 0;

    // ---- helpers ----
    auto poll_ingest = [&](u32 tag, float* kv) {
        ull* src = kb + (size_t)(tag & 1u) * HID + tid * 8;
        u32 pend = 0xFFu;
        for (;;) {
#pragma unroll
            for (int e = 0; e < 8; ++e) {
                if (pend & (1u << e)) {
                    ull v = __hip_atomic_load(&src[e], __ATOMIC_RELAXED,
                                              __HIP_MEMORY_SCOPE_AGENT);
                    if ((u32)(v >> 32) == tag) {
                        kv[e] = __uint_as_float((u32)v);
                        pend &= ~(1u << e);
                    }
                }
            }
            if (!pend) break;
            __builtin_amdgcn_s_sleep(1);
        }
    };
    auto emit_row = [&](float y) {     // lanes g==0 publish their row for round rnd
        if (g == 0) {
            ull pv = ((ull)rnd << 32) | (ull)__float_as_uint(y);
            __hip_atomic_store(kb + (size_t)(rnd & 1u) * HID + row, pv,
                               __ATOMIC_RELAXED, __HIP_MEMORY_SCOPE_AGENT);
        }
    };
    auto dot_ode = [&](float a, bool usek) -> float {
        float acc = 0.f;
#pragma unroll
        for (int jj = 0; jj < 16; ++jj) {
            const int c = g * 4 + jj * 128;
            float4 hv = *(const float4*)&h_lds[c];
            if (usek) {
                float4 k4 = *(const float4*)&k_lds[c];
                hv.x = fmaf(a, k4.x, hv.x); hv.y = fmaf(a, k4.y, hv.y);
                hv.z = fmaf(a, k4.z, hv.z); hv.w = fmaf(a, k4.w, hv.w);
            }
            acc = fmaf(wode[4*jj+0], hv.x, acc);
            acc = fmaf(wode[4*jj+1], hv.y, acc);
            acc = fmaf(wode[4*jj+2], hv.z, acc);
            acc = fmaf(wode[4*jj+3], hv.w, acc);
        }
        return acc;
    };

    // ---- round 1: h0 = tanh(W_in @ x[0] + b_in + b_hid) ----
    {
        float acc = 0.f;
#pragma unroll
        for (int jj = 0; jj < 4; ++jj) {
            const int c = g * 4 + jj * 128;
            float4 xv = *(const float4*)(x + c);
            acc = fmaf(win[4*jj+0], xv.x, acc);
            acc = fmaf(win[4*jj+1], xv.y, acc);
            acc = fmaf(win[4*jj+2], xv.z, acc);
            acc = fmaf(win[4*jj+3], xv.w, acc);
        }
        acc = reduce32(acc);
        rnd = 1;
        emit_row(tanhf(acc + bsum));
    }
    {   // ingest h0
        float kv[8]; poll_ingest(rnd, kv);
        const int c = tid * 8;
#pragma unroll
        for (int e = 0; e < 8; ++e) h_lds[c + e] = kv[e];
    }
    __syncthreads();

    // ---- main sequential loop ----
    for (int i = 1; i < TSTEPS; ++i) {
        const float dt  = (t[i] - t[i - 1]) / (float)nstep;
        const float dt2 = 0.5f * dt;
        const float dt3 = dt * (1.0f / 3.0f);
        const float dt6 = dt * (1.0f / 6.0f);

        for (int s = 0; s < nstep; ++s) {
            // --- stage A: k1 = f(h); fold previous substep's k4 first ---
            if (s > 0) {
                float kv[8]; poll_ingest(rnd, kv);
                const int c = tid * 8;
#pragma unroll
                for (int e = 0; e < 8; ++e)
                    h_lds[c + e] += hacc[c + e] + dt6 * kv[e];
            }
            __syncthreads();
            {
                float acc = reduce32(dot_ode(0.f, false));
                rnd++;
                emit_row(tanhf(acc + breg));
            }
            __syncthreads();

            // --- stages B,C,D: k2,k3,k4 ---
            for (int st = 0; st < 3; ++st) {
                const float wk = (st == 0) ? dt6 : dt3;
                const float a  = (st == 2) ? dt  : dt2;
                float kv[8]; poll_ingest(rnd, kv);
                const int c = tid * 8;
                if (st == 0) {
#pragma unroll
                    for (int e = 0; e < 8; ++e) {
                        k_lds[c + e] = kv[e];
                        hacc[c + e]  = wk * kv[e];
                    }
                } else {
#pragma unroll
                    for (int e = 0; e < 8; ++e) {
                        k_lds[c + e] = kv[e];
                        hacc[c + e] += wk * kv[e];
                    }
                }
                __syncthreads();
                float acc = reduce32(dot_ode(a, true));
                rnd++;
                emit_row(tanhf(acc + breg));
                __syncthreads();
            }
        }

        // --- stage E: fold k4; h_new = tanh(W_in x_i + b_in + W_hid h_i + b_hid) ---
        {
            float kv[8]; poll_ingest(rnd, kv);
            const int c = tid * 8;
#pragma unroll
            for (int e = 0; e < 8; ++e)
                h_lds[c + e] += hacc[c + e] + dt6 * kv[e];
            __syncthreads();

            float acc = 0.f;
#pragma unroll
            for (int jj = 0; jj < 16; ++jj) {
                const int cc = g * 4 + jj * 128;
                float4 wv = *(const float4*)(whid_row + cc);
                float4 hv = *(const float4*)&h_lds[cc];
                acc = fmaf(wv.x, hv.x, acc);
                acc = fmaf(wv.y, hv.y, acc);
                acc = fmaf(wv.z, hv.z, acc);
                acc = fmaf(wv.w, hv.w, acc);
            }
            const float* xr = x + (size_t)i * 512;
#pragma unroll
            for (int jj = 0; jj < 4; ++jj) {
                const int cc = g * 4 + jj * 128;
                float4 xv = *(const float4*)(xr + cc);
                acc = fmaf(win[4*jj+0], xv.x, acc);
                acc = fmaf(win[4*jj+1], xv.y, acc);
                acc = fmaf(win[4*jj+2], xv.z, acc);
                acc = fmaf(win[4*jj+3], xv.w, acc);
            }
            acc = reduce32(acc);
            rnd++;
            emit_row(tanhf(acc + bsum));
            __syncthreads();
        }
        // --- stage F: everyone ingests h_new ---
        {
            float kv[8]; poll_ingest(rnd, kv);
            const int c = tid * 8;
#pragma unroll
            for (int e = 0; e < 8; ++e) h_lds[c + e] = kv[e];
        }
        __syncthreads();
    }

    // ---- decode: out = W_dec @ h + b_dec (512 rows on blocks 0..63) ----
    if (bid < 64) {
        const int r2 = bid * 8 + rloc;
        const float* wd = W_dec + (size_t)r2 * HID;
        float acc = 0.f;
#pragma unroll
        for (int jj = 0; jj < 16; ++jj) {
            const int cc = g * 4 + jj * 128;
            float4 wv = *(const float4*)(wd + cc);
            float4 hv = *(const float4*)&h_lds[cc];
            acc = fmaf(wv.x, hv.x, acc);
            acc = fmaf(wv.y, hv.y, acc);
            acc = fmaf(wv.z, hv.z, acc);
            acc = fmaf(wv.w, hv.w, acc);
        }
        acc = reduce32(acc);
        if (g == 0) out[r2] = acc + b_dec[r2];   // fp32 store
    }
}

extern "C" void kernel_launch(void* const* d_in, const int* in_sizes, int n_in,
                              void* d_out, int out_size, void* d_ws, size_t ws_size,
                              hipStream_t stream) {
    const float* x     = (const float*)d_in[0];
    const float* t     = (const float*)d_in[1];
    const float* W_in  = (const float*)d_in[2];
    const float* b_in  = (const float*)d_in[3];
    const float* W_hid = (const float*)d_in[4];
    const float* b_hid = (const float*)d_in[5];
    const float* W_ode = (const float*)d_in[6];
    const float* b_ode = (const float*)d_in[7];
    const float* W_dec = (const float*)d_in[8];
    const float* b_dec = (const float*)d_in[9];
    const int*   nstep = (const int*)d_in[10];
    ull* kb = (ull*)d_ws;                       // 2 * 2048 * 8B = 32 KB
    float* out = (float*)d_out;                 // reference output dtype is fp32

    // Plain launch: grid(256) == #CUs, 24KB LDS, 1 block/CU -> all blocks
    // resident immediately; synchronization is via tagged atomic words in kb
    // (double-buffered), no grid.sync() needed. Graph-capture safe.
    ode_rnn_main<<<dim3(NBLK), dim3(NTHR), 0, stream>>>(
        x, t, W_in, b_in, W_hid, b_hid, W_ode, b_ode, W_dec, b_dec,
        nstep, kb, out);
}